// Round 4
// baseline (414.861 us; speedup 1.0000x reference)
//
#include <hip/hip_runtime.h>
#include <hip/hip_bf16.h>
#include <math.h>

#define N_AC  8192
#define N_BC  8192
#define T_K   52
#define T_PAD 64

#define KSPLIT 16                 // total K-way split (per-wave segments)
#define KSEG   (N_BC / KSPLIT)    // 512 k per wave
#define RSTRIDE 72                // LDS row stride in bf16 (144 B, 16B-aligned, 2-way banks)
#define TILE_BF16 (16 * RSTRIDE)  // one staging buffer (16 rows x 64 k + pad)

typedef __bf16 bf16x8 __attribute__((ext_vector_type(8)));
typedef __bf16 bf16x4 __attribute__((ext_vector_type(4)));
typedef float  f32x4  __attribute__((ext_vector_type(4)));

// ---------------------------------------------------------------------------
// Prep: x (N_BC, T_K) fp32 -> xT (T_PAD, N_BC) bf16, zero-padded t in [52,64).
// ---------------------------------------------------------------------------
__global__ void xpose_kernel(const float* __restrict__ x, __bf16* __restrict__ xT) {
    int gt = blockIdx.x * blockDim.x + threadIdx.x;   // 0 .. T_PAD*N_BC-1
    int b = gt & (N_BC - 1);
    int t = gt >> 13;                                  // N_BC = 2^13
    float v = (t < T_K) ? x[b * T_K + t] : 0.0f;
    xT[gt] = (__bf16)v;
}

// ---------------------------------------------------------------------------
// GEMM: grid (512, 4) x 256 thr. NO barriers. Each wave independently owns
// 16 AC rows x a 512-wide K segment (16-way K split overall).
//
// W loads are copy-style coalesced: per instruction, 4 consecutive lanes
// cover one fully-consumed 64B line of one row (16 full lines / instr).
// Loaded fp32 -> bf16 in-register -> per-wave double-buffered LDS tile
// (row stride 72 bf16 = 144 B: ds_read_b128-aligned, <=2-way bank alias).
// A-fragments then come from ds_read_b128; B-fragments from L2-resident xT.
//
// Fragment layouts (verified rounds 1-3):
//   A: lane holds A[m = lane&15][k = (lane>>4)*8 + j]
//   B: lane holds B[k = (lane>>4)*8 + j][n = lane&15]
//   D: lane holds D[row = (lane>>4)*4 + r][col = lane&15]
// ---------------------------------------------------------------------------
__global__ __launch_bounds__(256, 6) void ac_gemm_kernel(
    const float*  __restrict__ W,        // (N_AC, N_BC) fp32
    const __bf16* __restrict__ xT,       // (T_PAD, N_BC) bf16
    const float*  __restrict__ kern,     // (N_AC, T_K) fp32
    float*        __restrict__ partials) // (KSPLIT, N_AC)
{
    const int tid  = threadIdx.x;
    const int lane = tid & 63;
    const int wave = tid >> 6;
    const int quad = lane >> 4;
    const int l15  = lane & 15;
    const int a0   = blockIdx.x * 16;
    const int ksub = blockIdx.y * 4 + wave;     // 0..15
    const int kbeg = ksub * KSEG;

    __shared__ __bf16 As[4 * 2 * TILE_BF16];    // 4 waves x double buffer
    __bf16* tile0 = &As[wave * 2 * TILE_BF16];

    const int wr = lane >> 2;                   // staging row this lane loads
    const int wc = lane & 3;                    // float4 slot within 64B line
    const float* wbase = W + (size_t)(a0 + wr) * N_BC + wc * 4;

    f32x4 acc[4] = {};   // 4 t-tiles: [0,16),[16,32),[32,48),[48,64)

    #pragma unroll 2
    for (int it = 0; it < KSEG / 64; ++it) {
        const int kb = kbeg + it * 64;
        __bf16* tile = tile0 + (it & 1) * TILE_BF16;

        // ---- stage 16 rows x 64 floats, fully-coalesced 64B segments ----
        #pragma unroll
        for (int j = 0; j < 4; ++j) {
            float4 f = *(const float4*)(wbase + kb + j * 16);
            bf16x4 h;
            h[0] = (__bf16)f.x; h[1] = (__bf16)f.y;
            h[2] = (__bf16)f.z; h[3] = (__bf16)f.w;
            *(bf16x4*)&tile[wr * RSTRIDE + j * 16 + wc * 4] = h;
        }

        // ---- compute: 2 k-steps x 4 t-tiles ----
        #pragma unroll
        for (int s = 0; s < 2; ++s) {
            bf16x8 af = *(const bf16x8*)&tile[l15 * RSTRIDE + s * 32 + quad * 8];
            #pragma unroll
            for (int nt = 0; nt < 4; ++nt) {
                bf16x8 bf = *(const bf16x8*)(xT + (size_t)(nt * 16 + l15) * N_BC
                                             + kb + s * 32 + quad * 8);
                acc[nt] = __builtin_amdgcn_mfma_f32_16x16x32_bf16(af, bf, acc[nt], 0, 0, 0);
            }
        }
    }

    // ---- temporal weighting: p[r] = sum_t kern[row, t] * y[row, t] ----
    float p[4] = {0.f, 0.f, 0.f, 0.f};
    #pragma unroll
    for (int nt = 0; nt < 4; ++nt) {
        int t = nt * 16 + l15;
        if (t < T_K) {
            #pragma unroll
            for (int r = 0; r < 4; ++r) {
                int grow = a0 + quad * 4 + r;
                p[r] += acc[nt][r] * kern[grow * T_K + t];
            }
        }
    }
    #pragma unroll
    for (int m = 1; m <= 8; m <<= 1) {
        #pragma unroll
        for (int r = 0; r < 4; ++r) p[r] += __shfl_xor(p[r], m);
    }

    if (l15 == 0) {
        #pragma unroll
        for (int r = 0; r < 4; ++r)
            partials[ksub * N_AC + a0 + quad * 4 + r] = p[r];
    }
}

// ---------------------------------------------------------------------------
// Final: reduce K-split partials, fused sigmoid
// ---------------------------------------------------------------------------
__global__ void ac_final_kernel(const float* __restrict__ partials,
                                const float* __restrict__ slope,
                                const float* __restrict__ offs,
                                float* __restrict__ out) {
    int a = blockIdx.x * blockDim.x + threadIdx.x;
    if (a >= N_AC) return;
    float s = 0.f;
    #pragma unroll
    for (int ks = 0; ks < KSPLIT; ++ks) s += partials[ks * N_AC + a];
    float z = slope[a] * (s - offs[a]);
    out[a] = 1.0f / (1.0f + __expf(-z));
}

extern "C" void kernel_launch(void* const* d_in, const int* in_sizes, int n_in,
                              void* d_out, int out_size, void* d_ws, size_t ws_size,
                              hipStream_t stream) {
    const float* x     = (const float*)d_in[0];  // (N_BC, T_K)
    const float* W     = (const float*)d_in[1];  // (N_AC, N_BC)
    const float* kern  = (const float*)d_in[2];  // (N_AC, T_K)
    const float* slope = (const float*)d_in[3];  // (N_AC,)
    const float* offs  = (const float*)d_in[4];  // (N_AC,)
    float* out = (float*)d_out;

    __bf16* xT      = (__bf16*)d_ws;                                   // 1 MB
    float* partials = (float*)((char*)d_ws + (size_t)T_PAD * N_BC * sizeof(__bf16));

    xpose_kernel<<<dim3(T_PAD * N_BC / 256), dim3(256), 0, stream>>>(x, xT);
    ac_gemm_kernel<<<dim3(N_AC / 16, KSPLIT / 4), dim3(256), 0, stream>>>(
        W, xT, kern, partials);
    ac_final_kernel<<<dim3(N_AC / 256), dim3(256), 0, stream>>>(
        partials, slope, offs, out);
}

// Round 5
// 383.329 us; speedup vs baseline: 1.0823x; 1.0823x over previous
//
#include <hip/hip_runtime.h>
#include <hip/hip_bf16.h>
#include <math.h>

#define N_AC  8192
#define N_BC  8192
#define T_K   52
#define T_PAD 64

#define KSPLIT 16                 // K-way split; one k-range per WG
#define KSEG   (N_BC / KSPLIT)    // 512 k per wave
#define CHUNK  256                // k-width staged per iteration
#define NCHUNK (KSEG / CHUNK)     // 2
#define RSTRIDE 264               // LDS row stride in bf16 (528 B)

typedef __bf16 bf16x8 __attribute__((ext_vector_type(8)));
typedef __bf16 bf16x4 __attribute__((ext_vector_type(4)));
typedef float  f32x4  __attribute__((ext_vector_type(4)));

// ---------------------------------------------------------------------------
// Pack x into MFMA B-fragment order (bf16, t zero-padded to 64):
// group g = kblock*4 + nt  (kblock = k/32, 256 of them; nt = t-tile, 4)
// within group: lane (quad=lane>>4, l15=lane&15) holds 8 bf16 =
//   x[b = kblock*32 + quad*8 + j][t = nt*16 + l15],  j = 0..7
// -> every GEMM B-load is one fully-contiguous 1 KB wave load.
// ---------------------------------------------------------------------------
__global__ void bpack_kernel(const float* __restrict__ x, __bf16* __restrict__ Bp) {
    int gid   = blockIdx.x * blockDim.x + threadIdx.x;  // 65536 threads
    int lane  = gid & 63;
    int group = gid >> 6;            // 0..1023
    int kblock = group >> 2;
    int nt     = group & 3;
    int quad = lane >> 4;
    int l15  = lane & 15;
    int t  = nt * 16 + l15;
    int b0 = kblock * 32 + quad * 8;
    bf16x8 v;
    #pragma unroll
    for (int j = 0; j < 8; ++j) {
        float f = (t < T_K) ? x[(b0 + j) * T_K + t] : 0.0f;
        v[j] = (__bf16)f;
    }
    *(bf16x8*)(Bp + (size_t)group * 512 + lane * 8) = v;
}

// ---------------------------------------------------------------------------
// GEMM: grid (128, 16) x 256 thr. NO barriers. WG covers 64 AC rows; each of
// its 4 waves owns 16 rows; ALL waves sweep the SAME 512-wide k-range
// (ksub = blockIdx.y) -> B loads are identical across waves (L1 broadcast).
//
// Per 256-k chunk per wave:
//   - 16 row-contiguous 1 KB W loads (prefetched one chunk ahead in regs)
//   - cvt fp32->bf16, ds_write_b64 into private LDS tile (2-way banks, free)
//   - 8 k-steps: ds_read_b128 A-frag, 4 packed-B loads (L1-hot), 4 MFMAs
//
// Fragment layouts (verified rounds 1-4):
//   A: lane holds A[m = lane&15][k = (lane>>4)*8 + j]
//   B: lane holds B[k = (lane>>4)*8 + j][n = lane&15]
//   D: lane holds D[row = (lane>>4)*4 + r][col = lane&15]
// ---------------------------------------------------------------------------
__global__ __launch_bounds__(256, 4) void ac_gemm_kernel(
    const float*  __restrict__ W,        // (N_AC, N_BC) fp32
    const __bf16* __restrict__ Bp,       // packed B (1 MB)
    const float*  __restrict__ kern,     // (N_AC, T_K) fp32
    float*        __restrict__ partials) // (KSPLIT, N_AC)
{
    const int tid  = threadIdx.x;
    const int lane = tid & 63;
    const int wave = tid >> 6;
    const int quad = lane >> 4;
    const int l15  = lane & 15;
    const int a0   = blockIdx.x * 64 + wave * 16;   // this wave's 16 rows
    const int ksub = blockIdx.y;
    const int kbeg = ksub * KSEG;

    __shared__ __bf16 As[4 * 16 * RSTRIDE];         // 4 waves x 16x256 tile
    __bf16* tile = &As[wave * 16 * RSTRIDE];

    // W staging addresses: instr j = row a0+j, lane covers floats lane*4..+3
    const float* wbase = W + (size_t)a0 * N_BC + lane * 4;

    f32x4 acc[4] = {};   // 4 t-tiles: [0,16),[16,32),[32,48),[48,64)

    // prologue: prefetch chunk 0 into registers
    float4 pre[16];
    #pragma unroll
    for (int j = 0; j < 16; ++j)
        pre[j] = *(const float4*)(wbase + (size_t)j * N_BC + kbeg);

    for (int c = 0; c < NCHUNK; ++c) {
        const int kc = kbeg + c * CHUNK;

        // ---- commit prefetched chunk to LDS as bf16 ----
        #pragma unroll
        for (int j = 0; j < 16; ++j) {
            bf16x4 h;
            h[0] = (__bf16)pre[j].x; h[1] = (__bf16)pre[j].y;
            h[2] = (__bf16)pre[j].z; h[3] = (__bf16)pre[j].w;
            *(bf16x4*)&tile[j * RSTRIDE + lane * 4] = h;
        }

        // ---- prefetch next chunk ----
        if (c + 1 < NCHUNK) {
            #pragma unroll
            for (int j = 0; j < 16; ++j)
                pre[j] = *(const float4*)(wbase + (size_t)j * N_BC + kc + CHUNK);
        }

        // ---- compute: 8 k-steps x 4 t-tiles ----
        #pragma unroll
        for (int s = 0; s < 8; ++s) {
            bf16x8 af = *(const bf16x8*)&tile[l15 * RSTRIDE + s * 32 + quad * 8];
            const size_t kblock = (size_t)(kc >> 5) + s;
            #pragma unroll
            for (int nt = 0; nt < 4; ++nt) {
                bf16x8 bf = *(const bf16x8*)(Bp + (kblock * 4 + nt) * 512 + lane * 8);
                acc[nt] = __builtin_amdgcn_mfma_f32_16x16x32_bf16(af, bf, acc[nt], 0, 0, 0);
            }
        }
    }

    // ---- temporal weighting: p[r] = sum_t kern[row, t] * y[row, t] ----
    float p[4] = {0.f, 0.f, 0.f, 0.f};
    #pragma unroll
    for (int nt = 0; nt < 4; ++nt) {
        int t = nt * 16 + l15;
        if (t < T_K) {
            #pragma unroll
            for (int r = 0; r < 4; ++r) {
                int grow = a0 + quad * 4 + r;
                p[r] += acc[nt][r] * kern[grow * T_K + t];
            }
        }
    }
    #pragma unroll
    for (int m = 1; m <= 8; m <<= 1) {
        #pragma unroll
        for (int r = 0; r < 4; ++r) p[r] += __shfl_xor(p[r], m);
    }

    if (l15 == 0) {
        #pragma unroll
        for (int r = 0; r < 4; ++r)
            partials[ksub * N_AC + a0 + quad * 4 + r] = p[r];
    }
}

// ---------------------------------------------------------------------------
// Final: reduce K-split partials, fused sigmoid
// ---------------------------------------------------------------------------
__global__ void ac_final_kernel(const float* __restrict__ partials,
                                const float* __restrict__ slope,
                                const float* __restrict__ offs,
                                float* __restrict__ out) {
    int a = blockIdx.x * blockDim.x + threadIdx.x;
    if (a >= N_AC) return;
    float s = 0.f;
    #pragma unroll
    for (int ks = 0; ks < KSPLIT; ++ks) s += partials[ks * N_AC + a];
    float z = slope[a] * (s - offs[a]);
    out[a] = 1.0f / (1.0f + __expf(-z));
}

extern "C" void kernel_launch(void* const* d_in, const int* in_sizes, int n_in,
                              void* d_out, int out_size, void* d_ws, size_t ws_size,
                              hipStream_t stream) {
    const float* x     = (const float*)d_in[0];  // (N_BC, T_K)
    const float* W     = (const float*)d_in[1];  // (N_AC, N_BC)
    const float* kern  = (const float*)d_in[2];  // (N_AC, T_K)
    const float* slope = (const float*)d_in[3];  // (N_AC,)
    const float* offs  = (const float*)d_in[4];  // (N_AC,)
    float* out = (float*)d_out;

    __bf16* Bp      = (__bf16*)d_ws;                                   // 1 MB
    float* partials = (float*)((char*)d_ws + (size_t)1024 * 512 * sizeof(__bf16));

    bpack_kernel<<<dim3(65536 / 256), dim3(256), 0, stream>>>(x, Bp);
    ac_gemm_kernel<<<dim3(N_AC / 64, KSPLIT), dim3(256), 0, stream>>>(
        W, Bp, kern, partials);
    ac_final_kernel<<<dim3(N_AC / 256), dim3(256), 0, stream>>>(
        partials, slope, offs, out);
}